// Round 8
// baseline (765.289 us; speedup 1.0000x reference)
//
#include <hip/hip_runtime.h>
#include <math.h>

// Round 8: k-split/d-split multi-kernel resonator decoder (MI355X, gfx950).
// Per iteration exactly 2 kernels, and the all-to-all exchange volume is tiny:
//   k_simw : block g owns 4 codes; sims[b][4] = est(256 KB, L2-dedup) . T2g
//            row (64 KB, L2-hot) in fp32; w = exp2(c2*sims) (unnormalized
//            softmax: atan2 direction is scale-invariant) OR, at it==NI,
//            writes out = sims/4096 directly.
//   k_est  : block owns 16 dims (32 rows); re/im = W . T1 rows (DPP reduce);
//            est = (re,im)/|z| (no atan2); writes 1 KB est slice.
// Tables (bf16, built once): T1[j=2d+cs][k] k-contiguous for k_est;
// T2g[g=k/4][j][c=k%4] j-contiguous for k_simw. No P partials, no atomics.

#define KCODES 1024
#define DIMS   4096
#define BATCH  8
#define JROWS  (DIMS * 2)      // 8192 (cos,sin) rows
#define NITER_MAX 50           // device-side guard handles *nit_p < NITER_MAX

// ws float offsets (~33.9 MB total)
#define T1_SZF  (JROWS * KCODES / 2)        // bf16: 4,194,304 f32 slots (16 MB)
#define T2_OFF  (T1_SZF)
#define T2_SZF  (T1_SZF)                    // 16 MB
#define EST_OFF (T2_OFF + T2_SZF)
#define EST_SZ  (JROWS * BATCH)             // est[j][b] f32 (256 KB)
#define W_OFF   (EST_OFF + EST_SZ)          // W[b][k] f32 (32 KB)

#define C2 (0.00244140625f * 1.4426950408889634f)   // (10/4096)*log2(e)

// ---- bf16 helpers ----
__device__ __forceinline__ ushort f2bf(float x) {
  unsigned u = __float_as_uint(x);
  return (ushort)((u + 0x7FFFu + ((u >> 16) & 1u)) >> 16);   // RNE
}
__device__ __forceinline__ float bf2f(ushort u) {
  return __uint_as_float(((unsigned)u) << 16);
}

// ---- DPP wave64 sum: result valid in lane 63 ----
template <int CTRL>
__device__ __forceinline__ float dpp_add(float x) {
  int v = __builtin_amdgcn_update_dpp(0, __float_as_int(x), CTRL, 0xF, 0xF, false);
  return x + __int_as_float(v);
}
__device__ __forceinline__ float wave_sum64(float x) {
  x = dpp_add<0x111>(x);   // row_shr:1
  x = dpp_add<0x112>(x);   // row_shr:2
  x = dpp_add<0x114>(x);   // row_shr:4
  x = dpp_add<0x118>(x);   // row_shr:8
  x = dpp_add<0x142>(x);   // row_bcast:15
  x = dpp_add<0x143>(x);   // row_bcast:31
  return x;                // lane 63 = sum of all 64 lanes
}

// ---- one-time: T1[j][k] build via LDS tile transpose (r7-proven) ----
__global__ __launch_bounds__(256) void k_trig(const float* __restrict__ cb,
                                              float* __restrict__ ws) {
  __shared__ float lc[64][65], ls[64][65];
  const int t  = threadIdx.x;
  const int bk = blockIdx.x & 15;        // 16 k-tiles
  const int bd = blockIdx.x >> 4;        // 64 d-tiles
  const int k0 = bk * 64, d0 = bd * 64;
  const int c = t & 63;
  #pragma unroll
  for (int i = 0; i < 16; ++i) {
    const int r = (t >> 6) + i * 4;
    float a = cb[(size_t)(k0 + r) * DIMS + d0 + c];
    float s, cc; sincosf(a, &s, &cc);
    lc[r][c] = cc; ls[r][c] = s;
  }
  __syncthreads();
  ushort* T1 = (ushort*)ws;
  #pragma unroll
  for (int j = 0; j < 16; ++j) {
    const int dd = (t >> 6) + j * 4;
    T1[(size_t)((d0 + dd) * 2 + 0) * KCODES + k0 + c] = f2bf(lc[c][dd]);
    T1[(size_t)((d0 + dd) * 2 + 1) * KCODES + k0 + c] = f2bf(ls[c][dd]);
  }
}

// ---- one-time: T2g[g][j][c] build. Block g: 4 codebook rows via LDS. ----
__global__ __launch_bounds__(256) void k_trig2(const float* __restrict__ cb,
                                               float* __restrict__ ws) {
  __shared__ float cbl[4][DIMS];         // 64 KB
  const int t = threadIdx.x;
  const int g = blockIdx.x;              // codes 4g..4g+3
  #pragma unroll
  for (int c = 0; c < 4; ++c)
    #pragma unroll
    for (int q = 0; q < 4; ++q) {
      const int off = (q * 256 + t) * 4;
      *(float4*)&cbl[c][off] = *(const float4*)&cb[(size_t)(4 * g + c) * DIMS + off];
    }
  __syncthreads();

  // thread owns d-range [16t, 16t+16) -> contiguous 256 B of T2g row g
  ushort buf[128];                       // [ (2*dl+cs)*4 + c ]
  #pragma unroll
  for (int dl = 0; dl < 16; ++dl) {
    #pragma unroll
    for (int c = 0; c < 4; ++c) {
      float s, cc; sincosf(cbl[c][16 * t + dl], &s, &cc);
      buf[(2 * dl + 0) * 4 + c] = f2bf(cc);
      buf[(2 * dl + 1) * 4 + c] = f2bf(s);
    }
  }
  uint4* dst = (uint4*)((ushort*)(ws + T2_OFF) + (size_t)g * (JROWS * 4) + t * 128);
  const uint4* src = (const uint4*)buf;
  #pragma unroll
  for (int i = 0; i < 16; ++i) dst[i] = src[i];
}

// ---- one-time: est[j][b] from superposed ----
__global__ __launch_bounds__(256) void k_init(const float* __restrict__ sup,
                                              float* __restrict__ ws) {
  float* EST = ws + EST_OFF;
  const int i = blockIdx.x * 256 + threadIdx.x;   // 0..32767
  const int b = i >> 12, d = i & 4095;
  float s, c; sincosf(sup[(size_t)b * DIMS + d], &s, &c);
  EST[(2 * d + 0) * BATCH + b] = c;
  EST[(2 * d + 1) * BATCH + b] = s;
}

// ---- per-iter 1: sims + w for 4 codes (fp32, no cross-block reduce) ----
// 256 blocks x 512 thr; thread covers j = i*512+t, i=0..15.
__global__ __launch_bounds__(512) void k_simw(float* __restrict__ ws,
                                              const int* __restrict__ nit_p,
                                              float* __restrict__ out,
                                              int it) {
  const int NI = *nit_p;
  if (it > NI) return;
  const ushort* T2  = (const ushort*)(ws + T2_OFF);
  const float*  EST = ws + EST_OFF;
  float* W = ws + W_OFF;
  __shared__ float scr[8 * 32];

  const int t = threadIdx.x, lane = t & 63, wv = t >> 6;
  const int g = blockIdx.x;
  const ushort* trow = T2 + (size_t)g * (JROWS * 4);

  float acc[4][BATCH];                   // [c][b]
  #pragma unroll
  for (int c = 0; c < 4; ++c)
    #pragma unroll
    for (int b = 0; b < BATCH; ++b) acc[c][b] = 0.f;

  #pragma unroll 4
  for (int i = 0; i < 16; ++i) {
    const int j = i * 512 + t;
    const float4 e0 = *(const float4*)&EST[j * BATCH + 0];
    const float4 e1 = *(const float4*)&EST[j * BATCH + 4];
    const float ev[8] = {e0.x, e0.y, e0.z, e0.w, e1.x, e1.y, e1.z, e1.w};
    const ushort4 tu = *(const ushort4*)&trow[j * 4];
    const float tc[4] = {bf2f(tu.x), bf2f(tu.y), bf2f(tu.z), bf2f(tu.w)};
    #pragma unroll
    for (int c = 0; c < 4; ++c)
      #pragma unroll
      for (int b = 0; b < BATCH; ++b)
        acc[c][b] = fmaf(tc[c], ev[b], acc[c][b]);
  }

  #pragma unroll
  for (int c = 0; c < 4; ++c)
    #pragma unroll
    for (int b = 0; b < BATCH; ++b) {
      const float s = wave_sum64(acc[c][b]);
      if (lane == 63) scr[wv * 32 + c * BATCH + b] = s;
    }
  __syncthreads();

  if (t < 32) {
    float s = 0.f;
    #pragma unroll
    for (int w8 = 0; w8 < 8; ++w8) s += scr[w8 * 32 + t];
    const int c = t >> 3, b = t & 7;
    if (it == NI) out[b * KCODES + 4 * g + c] = s * (1.0f / (float)DIMS);
    else          W[b * KCODES + 4 * g + c] = exp2f(s * C2);
  }
}

// ---- per-iter 2: est update for 16 dims (r7-proven phase1 + write) ----
// 256 blocks x 512 thr; wave owns 4 of the block's 32 T1 rows.
__global__ __launch_bounds__(512) void k_est(float* __restrict__ ws,
                                             const int* __restrict__ nit_p,
                                             int it) {
  if (it >= *nit_p) return;
  const ushort* T1 = (const ushort*)ws;
  const float*  Wg = ws + W_OFF;
  float* EST = ws + EST_OFF;

  __shared__ float Wl[BATCH * KCODES];   // 32 KB
  __shared__ float est_l[32 * BATCH];

  const int t = threadIdx.x, lane = t & 63, wv = t >> 6;
  const int r0 = blockIdx.x * 32;

  #pragma unroll
  for (int j = 0; j < 4; ++j) {
    const int idx = (j * 512 + t) * 4;
    *(float4*)&Wl[idx] = *(const float4*)&Wg[idx];
  }
  __syncthreads();

  const int rw = wv * 4;
  float acc[4][BATCH];
  #pragma unroll
  for (int r = 0; r < 4; ++r)
    #pragma unroll
    for (int b = 0; b < BATCH; ++b) acc[r][b] = 0.f;

  #pragma unroll
  for (int c = 0; c < 4; ++c) {
    const int kk = c * 256 + lane * 4;
    float4 wr[BATCH];
    #pragma unroll
    for (int b = 0; b < BATCH; ++b)
      wr[b] = *(const float4*)&Wl[b * KCODES + kk];
    #pragma unroll
    for (int r = 0; r < 4; ++r) {
      const ushort4 tu = *(const ushort4*)&T1[(size_t)(r0 + rw + r) * KCODES + kk];
      const float4 tv = make_float4(bf2f(tu.x), bf2f(tu.y), bf2f(tu.z), bf2f(tu.w));
      #pragma unroll
      for (int b = 0; b < BATCH; ++b) {
        acc[r][b] = fmaf(wr[b].x, tv.x, acc[r][b]);
        acc[r][b] = fmaf(wr[b].y, tv.y, acc[r][b]);
        acc[r][b] = fmaf(wr[b].z, tv.z, acc[r][b]);
        acc[r][b] = fmaf(wr[b].w, tv.w, acc[r][b]);
      }
    }
  }
  #pragma unroll
  for (int r = 0; r < 4; ++r)
    #pragma unroll
    for (int b = 0; b < BATCH; ++b) {
      const float s = wave_sum64(acc[r][b]);
      if (lane == 63) est_l[(rw + r) * BATCH + b] = s;
    }
  __syncthreads();

  if (t < 128) {                         // normalize: (re,im)/|z|
    const int dl = t >> 3, b = t & 7;
    const float re = est_l[(2 * dl + 0) * BATCH + b];
    const float im = est_l[(2 * dl + 1) * BATCH + b];
    const float n2 = fmaf(re, re, im * im);
    float ec, es;
    if (n2 > 0.f) {
      const float inv = rsqrtf(n2);
      ec = re * inv; es = im * inv;
    } else { ec = 1.f; es = 0.f; }       // atan2(0,0) = 0
    est_l[(2 * dl + 0) * BATCH + b] = ec;
    est_l[(2 * dl + 1) * BATCH + b] = es;
  }
  __syncthreads();

  if (t < 256) EST[r0 * BATCH + t] = est_l[t];   // 1 KB coalesced slice store
}

extern "C" void kernel_launch(void* const* d_in, const int* in_sizes, int n_in,
                              void* d_out, int out_size, void* d_ws, size_t ws_size,
                              hipStream_t stream) {
  const float* sup = (const float*)d_in[0];
  const float* cbk = (const float*)d_in[1];
  const int*   nit = (const int*)d_in[2];
  float* outp = (float*)d_out;
  float* ws   = (float*)d_ws;

  hipLaunchKernelGGL(k_trig,  dim3(1024), dim3(256), 0, stream, cbk, ws);
  hipLaunchKernelGGL(k_trig2, dim3(256),  dim3(256), 0, stream, cbk, ws);
  hipLaunchKernelGGL(k_init,  dim3(128),  dim3(256), 0, stream, sup, ws);

  for (int it = 0; it < NITER_MAX; ++it) {
    hipLaunchKernelGGL(k_simw, dim3(256), dim3(512), 0, stream, ws, nit, outp, it);
    hipLaunchKernelGGL(k_est,  dim3(256), dim3(512), 0, stream, ws, nit, it);
  }
  hipLaunchKernelGGL(k_simw, dim3(256), dim3(512), 0, stream, ws, nit, outp, NITER_MAX);
}